// Round 8
// baseline (1097.646 us; speedup 1.0000x reference)
//
#include <hip/hip_runtime.h>
#include <stdint.h>
#include <math.h>

// Problem dims (fixed by reference setup_inputs)
#define NN 8
#define TT 256
#define BB 4
#define DD 512
#define VV 32000
#define MM (NN*TT*BB)          // 8192 rows

// MFMA GEMM tiling
#define TM 128
#define TN 128
#define VT 5                   // n-tiles swept per block
#define GX (VV/(TN*VT))        // 50
#define CHUNKS3 32             // 3-pass kernel: K=16 per chunk (2048 halves)
#define CHUNKS1 16             // 1-pass kernel: K=32 per chunk (4096 halves)

#define RCAP 2048              // max rescored rows (expect ~370)
#define MARGIN 3.0e5f          // scaled-units confidence margin (~25 sigma)

typedef _Float16 half8  __attribute__((ext_vector_type(8)));
typedef float    f32x4  __attribute__((ext_vector_type(4)));
typedef float    f32x16 __attribute__((ext_vector_type(16)));
typedef unsigned long long u64;

#define MFMA32(a,b,c) __builtin_amdgcn_mfma_f32_32x32x16_f16((a),(b),(c),0,0,0)
#define MFMA16(a,b,c) __builtin_amdgcn_mfma_f32_16x16x32_f16((a),(b),(c),0,0,0)

// ---- workspace layout ----
#define OFF_P1     0ull              // 64KB u64[8192]
#define OFF_P2     65536ull          // 64KB
#define OFF_PE     131072ull         // 64KB
#define OFF_FLAG   196608ull         // 32KB int[8192]
#define OFF_LIST   229376ull         // 8KB  int[2048]
#define OFF_CNT    237568ull         // 4KB pad
#define OFF_SCORES 241664ull         // 32KB
#define OFF_AH     294912ull
#define AH_SZ      8388608ull        // 8192*512*2 B
#define OFF_AL     (OFF_AH + AH_SZ)
#define OFF_WH     (OFF_AL + AH_SZ)
#define WH_SZ      32768000ull       // 32000*512*2 B
#define OFF_WL     (OFF_WH + WH_SZ)
#define OFF_CAH    (OFF_WL + WH_SZ)
#define CA_SZ      2097152ull        // 2048*512*2 B
#define OFF_CAL    (OFF_CAH + CA_SZ)
#define WS_NEED2   (OFF_CAL + CA_SZ)     // ~86.8 MB : full fast path
#define WS_NEED1   (OFF_WL + WH_SZ)      // ~82.6 MB : 3-pass-everywhere path

// ---------- helpers ----------

__device__ __forceinline__ uint32_t fkey(float v){
  uint32_t b = __float_as_uint(v);
  return b ^ ((b & 0x80000000u) ? 0xFFFFFFFFu : 0x80000000u);
}
__device__ __forceinline__ float unfkey(uint32_t k){
  uint32_t b = (k & 0x80000000u) ? (k ^ 0x80000000u) : ~k;
  return __uint_as_float(b);
}

__device__ __forceinline__ uint32_t rotl32(uint32_t x, int r){
  return (x << r) | (x >> (32 - r));
}
__device__ __forceinline__ void threefry2x32(uint32_t k0, uint32_t k1,
                                             uint32_t& x0, uint32_t& x1){
  const uint32_t ks0 = k0, ks1 = k1, ks2 = k0 ^ k1 ^ 0x1BD11BDAu;
  x0 += ks0; x1 += ks1;
  x0 += x1; x1 = rotl32(x1,13); x1 ^= x0;
  x0 += x1; x1 = rotl32(x1,15); x1 ^= x0;
  x0 += x1; x1 = rotl32(x1,26); x1 ^= x0;
  x0 += x1; x1 = rotl32(x1, 6); x1 ^= x0;
  x0 += ks1; x1 += ks2 + 1u;
  x0 += x1; x1 = rotl32(x1,17); x1 ^= x0;
  x0 += x1; x1 = rotl32(x1,29); x1 ^= x0;
  x0 += x1; x1 = rotl32(x1,16); x1 ^= x0;
  x0 += x1; x1 = rotl32(x1,24); x1 ^= x0;
  x0 += ks2; x1 += ks0 + 2u;
  x0 += x1; x1 = rotl32(x1,13); x1 ^= x0;
  x0 += x1; x1 = rotl32(x1,15); x1 ^= x0;
  x0 += x1; x1 = rotl32(x1,26); x1 ^= x0;
  x0 += x1; x1 = rotl32(x1, 6); x1 ^= x0;
  x0 += ks0; x1 += ks1 + 3u;
  x0 += x1; x1 = rotl32(x1,17); x1 ^= x0;
  x0 += x1; x1 = rotl32(x1,29); x1 ^= x0;
  x0 += x1; x1 = rotl32(x1,16); x1 ^= x0;
  x0 += x1; x1 = rotl32(x1,24); x1 ^= x0;
  x0 += ks1; x1 += ks2 + 4u;
  x0 += x1; x1 = rotl32(x1,13); x1 ^= x0;
  x0 += x1; x1 = rotl32(x1,15); x1 ^= x0;
  x0 += x1; x1 = rotl32(x1,26); x1 ^= x0;
  x0 += x1; x1 = rotl32(x1, 6); x1 ^= x0;
  x0 += ks2; x1 += ks0 + 5u;
}

__device__ __forceinline__ float uniform_from_bits(uint32_t bits){
  return __uint_as_float((bits >> 9) | 0x3f800000u) - 1.0f;
}

// async 16B global -> LDS (global addr per-lane, LDS dest wave-uniform + lane*16)
__device__ __forceinline__ void gload16(const _Float16* g, _Float16* l){
  __builtin_amdgcn_global_load_lds(
      (const __attribute__((address_space(1))) uint32_t*)g,
      (__attribute__((address_space(3))) uint32_t*)l, 16, 0, 0);
}

// ---------- kernel: init all header accumulators ----------
__global__ void init_kernel(u64* p1, u64* p2, u64* pE, int* flag, unsigned int* cnt){
  int i = blockIdx.x * blockDim.x + threadIdx.x;
  if (i < MM){ p1[i] = 0ULL; p2[i] = 0ULL; pE[i] = 0ULL; flag[i] = 0; }
  if (i == 0) *cnt = 0u;
}

// ---------- conversion: fp32 [rows,512] -> split-f16 planes, tile layout ------
// hi = f16(x*scale), lo = f16(x*scale - hi) [natural residual].
// Plane chunk c = rt*8192 + kc*128 + rin (kc=k/8 in 0..63), 8 halves each.
__global__ __launch_bounds__(256)
void convert_kernel(const float* __restrict__ src,
                    _Float16* __restrict__ hi, _Float16* __restrict__ lo,
                    float scale){
  const int k0 = blockIdx.x & 15;       // 32-k slab
  const int rt = blockIdx.x >> 4;
  __shared__ _Float16 hbuf[4096], lbuf[4096];
  const int t = threadIdx.x;
  #pragma unroll
  for (int i = 0; i < 4; ++i){
    const int f = i * 256 + t;
    const int rin = f >> 3, c4 = f & 7;
    const float4 v4 = *(const float4*)&src[(size_t)(rt*128+rin)*DD + k0*32 + c4*4];
    const int base = (c4 >> 1) * 1024 + rin * 8 + (c4 & 1) * 4;
    float vv[4] = {v4.x, v4.y, v4.z, v4.w};
    #pragma unroll
    for (int j = 0; j < 4; ++j){
      const float s = vv[j] * scale;
      const _Float16 hh = (_Float16)s;
      hbuf[base + j] = hh;
      lbuf[base + j] = (_Float16)(s - (float)hh);
    }
  }
  __syncthreads();
  const size_t ob = ((size_t)rt * 8192 + (size_t)k0 * 512) * 8;
  #pragma unroll
  for (int i = 0; i < 2; ++i){
    const int cl = i * 256 + t;
    *(half8*)&hi[ob + (size_t)cl * 8] = *(const half8*)&hbuf[cl * 8];
    *(half8*)&lo[ob + (size_t)cl * 8] = *(const half8*)&lbuf[cl * 8];
  }
}

// ---------- kernel A: 1-pass hi*hi MFMA GEMM + top-2 tracking epilogue --------
// K=32 chunks, double-buffered; 34KB LDS -> 4 blocks/CU at (256,4).
__global__ __launch_bounds__(256, 4)
void gemm1_kernel(const _Float16* __restrict__ Ahp, const _Float16* __restrict__ Whp,
                  u64* __restrict__ p1, u64* __restrict__ p2){
  __shared__ __align__(16) _Float16 sAh[2][4096], sBh[2][4096];
  __shared__ u64 lmax1[TM], lmax2[TM];

  const int tid = threadIdx.x, wid = tid >> 6, lane = tid & 63;
  const int l31 = lane & 31, lhi = lane >> 5;
  const int wave_m = (wid & 1) * 64, wave_n = (wid >> 1) * 64;
  const int by = blockIdx.x;            // row-tile (fastest -> same-XCD A reuse)
  const int bx = blockIdx.y;            // W-group

  if (tid < TM){ lmax1[tid] = 0ULL; lmax2[tid] = 0ULL; }

  // staging: wid0/1 -> sAh halves, wid2/3 -> sBh halves
  const int half_off = (wid & 1) * 2048;

  for (int vt = 0; vt < VT; ++vt){
    const int nt = bx * VT + vt;

    f32x16 acc[2][2];
    #pragma unroll
    for (int i = 0; i < 2; ++i)
      #pragma unroll
      for (int j = 0; j < 2; ++j) acc[i][j] = (f32x16)0.0f;

    const _Float16* gplane = (wid < 2) ? Ahp + (size_t)by * 65536
                                       : Whp + (size_t)nt * 65536;
    _Float16* stg0 = ((wid < 2) ? sAh[0] : sBh[0]) + half_off;
    _Float16* stg1 = ((wid < 2) ? sAh[1] : sBh[1]) + half_off;

    { // stage chunk 0
      const _Float16* g = gplane + half_off + lane * 8;
      #pragma unroll
      for (int j = 0; j < 4; ++j) gload16(g + j * 512, stg0 + j * 512);
    }

    for (int kk = 0; kk < CHUNKS1; ++kk){
      __syncthreads();                  // buf[kk&1] ready
      if (kk < CHUNKS1 - 1){
        const _Float16* g = gplane + (size_t)(kk + 1) * 4096 + half_off + lane * 8;
        _Float16* s = (kk & 1) ? stg0 : stg1;
        #pragma unroll
        for (int j = 0; j < 4; ++j) gload16(g + j * 512, s + j * 512);
      }
      const int cb = kk & 1;

      // chunk layout [kc 4][row 128][8]; MFMA ks: kc = ks*2 + lhi
      half8 fah[2][2], fbh[2][2];
      #pragma unroll
      for (int ks = 0; ks < 2; ++ks){
        const int kcb = (ks * 2 + lhi) * 128;
        #pragma unroll
        for (int t = 0; t < 2; ++t){
          fah[ks][t] = *(const half8*)&sAh[cb][(kcb + wave_m + t * 32 + l31) * 8];
          fbh[ks][t] = *(const half8*)&sBh[cb][(kcb + wave_n + t * 32 + l31) * 8];
        }
      }
      #pragma unroll
      for (int ks = 0; ks < 2; ++ks)
        #pragma unroll
        for (int ti = 0; ti < 2; ++ti)
          #pragma unroll
          for (int tj = 0; tj < 2; ++tj)
            acc[ti][tj] = MFMA32(fah[ks][ti], fbh[ks][tj], acc[ti][tj]);
    }

    // top-2 epilogue. C/D: col=lane&31, row=(v&3)+8*(v>>2)+4*lhi.
    const int ncol0 = nt * TN + wave_n;
    #pragma unroll
    for (int ti = 0; ti < 2; ++ti){
      #pragma unroll
      for (int v = 0; v < 16; ++v){
        const int mloc = wave_m + ti * 32 + (v & 3) + 8 * (v >> 2) + 4 * lhi;
        u64 ca = ((u64)fkey(acc[ti][0][v]) << 32) | (u64)(~(uint32_t)(ncol0 + l31));
        u64 cb2 = ((u64)fkey(acc[ti][1][v]) << 32) | (u64)(~(uint32_t)(ncol0 + 32 + l31));
        u64 q1 = ca > cb2 ? ca : cb2;
        u64 q2 = ca > cb2 ? cb2 : ca;
        #pragma unroll
        for (int m = 16; m > 0; m >>= 1){     // pairwise top-2 over 32-lane group
          u64 o1 = __shfl_xor(q1, m, 64);
          u64 o2 = __shfl_xor(q2, m, 64);
          if (o1 > q1){ q2 = (q1 > o2) ? q1 : o2; q1 = o1; }
          else        { q2 = (q2 > o1) ? q2 : o1; }
        }
        if (l31 == 0){
          u64 old = atomicMax(&lmax1[mloc], q1);
          u64 loser = old < q1 ? old : q1;
          atomicMax(&lmax2[mloc], loser);
          atomicMax(&lmax2[mloc], q2);
        }
      }
    }
  }

  __syncthreads();
  if (tid < TM){
    const int g = by * TM + tid;
    u64 l1 = lmax1[tid], l2 = lmax2[tid];
    u64 old = atomicMax(&p1[g], l1);
    u64 loser = old < l1 ? old : l1;
    atomicMax(&p2[g], loser);
    atomicMax(&p2[g], l2);
  }
}

// ---------- kernel: resolve confident vs borderline rows ----------
__global__ void resolve_kernel(const u64* __restrict__ p1, const u64* __restrict__ p2,
                               int* __restrict__ flag, int* __restrict__ list,
                               unsigned int* __restrict__ cnt){
  const int r = blockIdx.x * blockDim.x + threadIdx.x;
  if (r >= MM) return;
  const float f1 = unfkey((uint32_t)(p1[r] >> 32));
  const float f2 = unfkey((uint32_t)(p2[r] >> 32));
  if (f1 - f2 <= MARGIN){
    const unsigned int idx = atomicAdd(cnt, 1u);
    if (idx < RCAP){ list[idx] = r; flag[r] = 1; }
  }
}

// ---------- kernel: compact borderline rows' planes into CA tiles ----------
__global__ void compact_kernel(const _Float16* __restrict__ Ahp,
                               const _Float16* __restrict__ Alp,
                               _Float16* __restrict__ CAh, _Float16* __restrict__ CAl,
                               const int* __restrict__ list,
                               const unsigned int* __restrict__ cnt){
  const int cid = blockIdx.x * 256 + threadIdx.x;   // 0..131071 (2048 rows x 64 chunks)
  const int i = cid >> 6, kc = cid & 63;
  const unsigned int c = *cnt;
  const unsigned int lim = ((c < RCAP ? c : RCAP) + 127u) & ~127u;
  if ((unsigned int)i >= lim) return;
  const int g = ((unsigned int)i < c) ? list[i] : list[0];
  const size_t src = ((size_t)(g >> 7) * 8192 + (size_t)kc * 128 + (g & 127)) * 8;
  const size_t dst = ((size_t)(i >> 7) * 8192 + (size_t)kc * 128 + (i & 127)) * 8;
  *(half8*)&CAh[dst] = *(const half8*)&Ahp[src];
  *(half8*)&CAl[dst] = *(const half8*)&Alp[src];
}

// ---------- kernel B: 3-pass split-f16 GEMM + argmax (full or gathered) -------
// acc = ah*bh + ah*bl + al*bh (single accumulator; round-7-verified).
__global__ __launch_bounds__(256, 4)
void gemm3_kernel(const _Float16* __restrict__ Ahp, const _Float16* __restrict__ Alp,
                  const _Float16* __restrict__ Whp, const _Float16* __restrict__ Wlp,
                  u64* __restrict__ out,
                  const int* __restrict__ rowlist,
                  const unsigned int* __restrict__ cntp){
  if (cntp && (unsigned int)(blockIdx.x * TM) >= *cntp) return;

  __shared__ __align__(16) _Float16 sAh[2][2048], sAl[2][2048], sBh[2][2048], sBl[2][2048];
  __shared__ u64 lmax[TM];

  const int tid = threadIdx.x, wid = tid >> 6, lane = tid & 63;
  const int l31 = lane & 31, lhi = lane >> 5;
  const int wave_m = (wid & 1) * 64, wave_n = (wid >> 1) * 64;
  const int by = blockIdx.x;
  const int bx = blockIdx.y;

  if (tid < TM) lmax[tid] = 0ULL;

  _Float16* stg0 = (wid == 0) ? sAh[0] : (wid == 1) ? sAl[0] : (wid == 2) ? sBh[0] : sBl[0];
  _Float16* stg1 = (wid == 0) ? sAh[1] : (wid == 1) ? sAl[1] : (wid == 2) ? sBh[1] : sBl[1];

  for (int vt = 0; vt < VT; ++vt){
    const int nt = bx * VT + vt;

    f32x16 acc[2][2];
    #pragma unroll
    for (int i = 0; i < 2; ++i)
      #pragma unroll
      for (int j = 0; j < 2; ++j) acc[i][j] = (f32x16)0.0f;

    const _Float16* gbase =
        (wid == 0) ? Ahp + (size_t)by * 65536 : (wid == 1) ? Alp + (size_t)by * 65536
      : (wid == 2) ? Whp + (size_t)nt * 65536 :              Wlp + (size_t)nt * 65536;

    {
      const _Float16* g = gbase + lane * 8;
      #pragma unroll
      for (int j = 0; j < 4; ++j) gload16(g + j * 512, stg0 + j * 512);
    }

    for (int kk = 0; kk < CHUNKS3; ++kk){
      __syncthreads();
      if (kk < CHUNKS3 - 1){
        const _Float16* g = gbase + (size_t)(kk + 1) * 2048 + lane * 8;
        _Float16* s = (kk & 1) ? stg0 : stg1;
        #pragma unroll
        for (int j = 0; j < 4; ++j) gload16(g + j * 512, s + j * 512);
      }
      const int cb = kk & 1;

      half8 fah[2], fal[2], fbh[2], fbl[2];
      #pragma unroll
      for (int t = 0; t < 2; ++t){
        const int ra = lhi * 128 + wave_m + t * 32 + l31;
        const int rb = lhi * 128 + wave_n + t * 32 + l31;
        fah[t] = *(const half8*)&sAh[cb][ra * 8];
        fal[t] = *(const half8*)&sAl[cb][ra * 8];
        fbh[t] = *(const half8*)&sBh[cb][rb * 8];
        fbl[t] = *(const half8*)&sBl[cb][rb * 8];
      }
      #pragma unroll
      for (int ti = 0; ti < 2; ++ti)
        #pragma unroll
        for (int tj = 0; tj < 2; ++tj){
          acc[ti][tj] = MFMA32(fah[ti], fbh[tj], acc[ti][tj]);
          acc[ti][tj] = MFMA32(fah[ti], fbl[tj], acc[ti][tj]);
          acc[ti][tj] = MFMA32(fal[ti], fbh[tj], acc[ti][tj]);
        }
    }

    const int ncol0 = nt * TN + wave_n;
    #pragma unroll
    for (int ti = 0; ti < 2; ++ti){
      #pragma unroll
      for (int v = 0; v < 16; ++v){
        const int mloc = wave_m + ti * 32 + (v & 3) + 8 * (v >> 2) + 4 * lhi;
        u64 best = 0ULL;
        #pragma unroll
        for (int tj = 0; tj < 2; ++tj){
          const int col = ncol0 + tj * 32 + l31;
          const u64 p = ((u64)fkey(acc[ti][tj][v]) << 32) | (u64)(~(uint32_t)col);
          if (p > best) best = p;
        }
        #pragma unroll
        for (int m = 16; m > 0; m >>= 1){
          const u64 o = __shfl_xor(best, m, 64);
          if (o > best) best = o;
        }
        if (l31 == 0) atomicMax(&lmax[mloc], best);
      }
    }
  }

  __syncthreads();
  if (tid < TM){
    int g;
    if (rowlist){
      const int i = by * TM + tid;
      const unsigned int c = *cntp;
      g = ((unsigned int)i < c) ? rowlist[i] : rowlist[0];
    } else {
      g = by * TM + tid;
    }
    atomicMax(&out[g], lmax[tid]);
  }
}

// ---------- fallback (round-3 verified): in-loop-convert GEMM ----------
__device__ __forceinline__ void cvt8(const float4& p, const float4& q, float scale,
                                     half8& h, half8& l){
  float v[8] = {p.x,p.y,p.z,p.w,q.x,q.y,q.z,q.w};
  #pragma unroll
  for (int j = 0; j < 8; ++j){
    const float s = v[j] * scale;
    const _Float16 hh = (_Float16)s;
    h[j] = hh;
    l[j] = (_Float16)((s - (float)hh) * 4096.0f);
  }
}

#define FBK 32
__global__ __launch_bounds__(256, 2)
void gemm_fallback_kernel(const float* __restrict__ A,
                          const float* __restrict__ W,
                          u64* __restrict__ packed){
  __shared__ __align__(16) _Float16 Ah[TM][40];
  __shared__ __align__(16) _Float16 Al[TM][40];
  __shared__ __align__(16) _Float16 Bh[TN][40];
  __shared__ __align__(16) _Float16 Bl[TN][40];
  __shared__ u64 lmax[TM];

  const int tid   = threadIdx.x;
  const int mtile = blockIdx.y * TM;
  const int wid    = tid >> 6;
  const int lane   = tid & 63;
  const int lm     = lane & 15;
  const int lk     = lane >> 4;
  const int wave_m = (wid & 1) * 64;
  const int wave_n = (wid >> 1) * 64;
  const int srow = tid >> 2;
  const int skc  = (tid & 3) * 8;

  if (tid < TM) lmax[tid] = 0ULL;

  for (int vt = 0; vt < VT; ++vt){
    const int ntile = (blockIdx.x * VT + vt) * TN;
    f32x4 acc1[4][4], acc2[4][4];
    #pragma unroll
    for (int i = 0; i < 4; ++i)
      #pragma unroll
      for (int j = 0; j < 4; ++j){ acc1[i][j] = (f32x4)0.0f; acc2[i][j] = (f32x4)0.0f; }

    for (int k0 = 0; k0 < DD; k0 += FBK){
      const float* pa0 = &A[(size_t)(mtile + srow     ) * DD + k0 + skc];
      const float* pa1 = &A[(size_t)(mtile + srow + 64) * DD + k0 + skc];
      const float* pb0 = &W[(size_t)(ntile + srow     ) * DD + k0 + skc];
      const float* pb1 = &W[(size_t)(ntile + srow + 64) * DD + k0 + skc];
      const float4 a00 = *(const float4*)(pa0), a01 = *(const float4*)(pa0 + 4);
      const float4 a10 = *(const float4*)(pa1), a11 = *(const float4*)(pa1 + 4);
      const float4 b00 = *(const float4*)(pb0), b01 = *(const float4*)(pb0 + 4);
      const float4 b10 = *(const float4*)(pb1), b11 = *(const float4*)(pb1 + 4);

      __syncthreads();
      half8 h, l;
      cvt8(a00, a01, 4096.0f,  h, l);
      *(half8*)&Ah[srow     ][skc] = h; *(half8*)&Al[srow     ][skc] = l;
      cvt8(a10, a11, 4096.0f,  h, l);
      *(half8*)&Ah[srow + 64][skc] = h; *(half8*)&Al[srow + 64][skc] = l;
      cvt8(b00, b01, 16384.0f, h, l);
      *(half8*)&Bh[srow     ][skc] = h; *(half8*)&Bl[srow     ][skc] = l;
      cvt8(b10, b11, 16384.0f, h, l);
      *(half8*)&Bh[srow + 64][skc] = h; *(half8*)&Bl[srow + 64][skc] = l;
      __syncthreads();

      half8 ah[4], al[4], bh[4], bl[4];
      #pragma unroll
      for (int ti = 0; ti < 4; ++ti){
        const int r = wave_m + ti * 16 + lm;
        ah[ti] = *(const half8*)&Ah[r][lk * 8];
        al[ti] = *(const half8*)&Al[r][lk * 8];
      }
      #pragma unroll
      for (int tj = 0; tj < 4; ++tj){
        const int r = wave_n + tj * 16 + lm;
        bh[tj] = *(const half8*)&Bh[r][lk * 8];
        bl[tj] = *(const half8*)&Bl[r][lk * 8];
      }
      #pragma unroll
      for (int ti = 0; ti < 4; ++ti)
        #pragma unroll
        for (int tj = 0; tj < 4; ++tj){
          acc1[ti][tj] = MFMA16(ah[ti], bh[tj], acc1[ti][tj]);
          acc2[ti][tj] = MFMA16(ah[ti], bl[tj], acc2[ti][tj]);
          acc2[ti][tj] = MFMA16(al[ti], bh[tj], acc2[ti][tj]);
        }
    }

    #pragma unroll
    for (int ti = 0; ti < 4; ++ti){
      #pragma unroll
      for (int v = 0; v < 4; ++v){
        const int mloc = wave_m + ti * 16 + lk * 4 + v;
        u64 best = 0ULL;
        #pragma unroll
        for (int tj = 0; tj < 4; ++tj){
          const int col = ntile + wave_n + tj * 16 + lm;
          const float lg = acc1[ti][tj][v] + acc2[ti][tj][v] * (1.0f/4096.0f);
          const u64 p = ((u64)fkey(lg) << 32) | (u64)(~(uint32_t)col);
          if (p > best) best = p;
        }
        atomicMax(&lmax[mloc], best);
      }
    }
  }

  __syncthreads();
  if (tid < TM) atomicMax(&packed[mtile + tid], lmax[tid]);
}

// ---------- kernel: scores[r] = sqrt(D) * dot(outputs[n,t,:], W[argmax_r]) ----
__global__ __launch_bounds__(256)
void score_kernel(const float* __restrict__ outputs,
                  const float* __restrict__ W,
                  const u64* __restrict__ p1, const u64* __restrict__ pE,
                  const int* __restrict__ flag,
                  float* __restrict__ scores){
  const int wave = threadIdx.x >> 6;
  const int lane = threadIdx.x & 63;
  const int r = blockIdx.x * 4 + wave;
  const u64 pk = flag[r] ? pE[r] : p1[r];
  const uint32_t idx = ~(uint32_t)pk;
  const int n = r >> 10;
  const int t = (r >> 2) & (TT - 1);
  const float* ov = outputs + ((size_t)(n * TT + t) << 9);
  const float* wv = W + (size_t)idx * DD;
  float s = 0.0f;
  #pragma unroll
  for (int j = 0; j < 8; ++j){
    const int d = lane + j * 64;
    s = fmaf(ov[d], wv[d], s);
  }
  #pragma unroll
  for (int off = 32; off > 0; off >>= 1) s += __shfl_down(s, off);
  if (lane == 0) scores[r] = s * 22.62741699796952f;  // float32(sqrt(512))
}

// ---------- kernel: sequential accept/reject scan + mask scatter ----------
__global__ __launch_bounds__(256)
void scan_kernel(const float* __restrict__ scores, float* __restrict__ mask_out){
  __shared__ float sc[MM];
  __shared__ float uu[TT * NN];

  const int tid = threadIdx.x;

  for (int i = tid; i < MM; i += 256){
    mask_out[i] = 0.0f;
    sc[i] = scores[i];
  }

  // Partitionable threefry (JAX >= 0.4.36): key' = tf2x32((0,42),(0,t));
  // element n: (o0,o1) = tf2x32(key',(0,n)); bits = o0^o1.
  {
    const int t = tid;
    uint32_t k0 = 0u, k1 = (uint32_t)t;
    threefry2x32(0u, 42u, k0, k1);
    #pragma unroll
    for (int n = 0; n < NN; ++n){
      uint32_t x0 = 0u, x1 = (uint32_t)n;
      threefry2x32(k0, k1, x0, x1);
      uu[t * NN + n] = uniform_from_bits(x0 ^ x1);
    }
  }
  __syncthreads();

  if (tid < NN){
    const int n = tid;
    int x = 0, y = 0;
    for (int t = 0; t < TT; ++t){
      const int idx0 = x * BB + y;
      mask_out[n * (TT * BB) + idx0] = 1.0f;
      const float scx0 = sc[n * (TT * BB) + idx0];
      const float scx1 = sc[n * (TT * BB) + t * BB];
      const float prob = 1.0f / (1.0f + expf(-((scx0 - scx1) / 10.0f)));
      int accept = (uu[t * NN + n] < prob) ? 1 : 0;
      if (y + accept >= BB) accept = 0;
      y = (y + accept) * accept;
      x = x * accept + (t + 1) * (1 - accept);
    }
  }
}

// ---------- launcher ----------
extern "C" void kernel_launch(void* const* d_in, const int* in_sizes, int n_in,
                              void* d_out, int out_size, void* d_ws, size_t ws_size,
                              hipStream_t stream){
  const float* outputs       = (const float*)d_in[0];   // [8,256,512]
  const float* block_outputs = (const float*)d_in[1];   // [8,256,4,512]
  const float* W             = (const float*)d_in[2];   // [32000,512]

  u64* p1   = (u64*)((char*)d_ws + OFF_P1);
  u64* p2   = (u64*)((char*)d_ws + OFF_P2);
  u64* pE   = (u64*)((char*)d_ws + OFF_PE);
  int* flag = (int*)((char*)d_ws + OFF_FLAG);
  int* list = (int*)((char*)d_ws + OFF_LIST);
  unsigned int* cnt = (unsigned int*)((char*)d_ws + OFF_CNT);
  float* scores = (float*)((char*)d_ws + OFF_SCORES);

  init_kernel<<<MM / 256, 256, 0, stream>>>(p1, p2, pE, flag, cnt);

  if (ws_size >= WS_NEED2){
    _Float16* Ahp = (_Float16*)((char*)d_ws + OFF_AH);
    _Float16* Alp = (_Float16*)((char*)d_ws + OFF_AL);
    _Float16* Whp = (_Float16*)((char*)d_ws + OFF_WH);
    _Float16* Wlp = (_Float16*)((char*)d_ws + OFF_WL);
    _Float16* CAh = (_Float16*)((char*)d_ws + OFF_CAH);
    _Float16* CAl = (_Float16*)((char*)d_ws + OFF_CAL);
    convert_kernel<<<(MM / 128) * 16, 256, 0, stream>>>(block_outputs, Ahp, Alp, 4096.0f);
    convert_kernel<<<(VV / 128) * 16, 256, 0, stream>>>(W, Whp, Wlp, 16384.0f);
    // pass 1: hi*hi approximate logits + top-2 per row
    gemm1_kernel<<<dim3(MM / TM, GX), 256, 0, stream>>>(Ahp, Whp, p1, p2);
    // flag rows whose top-2 gap is within the error margin
    resolve_kernel<<<MM / 256, 256, 0, stream>>>(p1, p2, flag, list, cnt);
    // gather borderline rows, exact 3-pass rescore of those rows only
    compact_kernel<<<(RCAP * 64) / 256, 256, 0, stream>>>(Ahp, Alp, CAh, CAl, list, cnt);
    gemm3_kernel<<<dim3(RCAP / TM, GX), 256, 0, stream>>>(CAh, CAl, Whp, Wlp, pE, list, cnt);
  } else if (ws_size >= WS_NEED1){
    _Float16* Ahp = (_Float16*)((char*)d_ws + OFF_AH);
    _Float16* Alp = (_Float16*)((char*)d_ws + OFF_AL);
    _Float16* Whp = (_Float16*)((char*)d_ws + OFF_WH);
    _Float16* Wlp = (_Float16*)((char*)d_ws + OFF_WL);
    convert_kernel<<<(MM / 128) * 16, 256, 0, stream>>>(block_outputs, Ahp, Alp, 4096.0f);
    convert_kernel<<<(VV / 128) * 16, 256, 0, stream>>>(W, Whp, Wlp, 16384.0f);
    gemm3_kernel<<<dim3(MM / TM, GX), 256, 0, stream>>>(Ahp, Alp, Whp, Wlp, p1,
                                                        nullptr, nullptr);
  } else {
    gemm_fallback_kernel<<<dim3(GX, MM / TM), 256, 0, stream>>>(block_outputs, W, p1);
  }

  score_kernel<<<MM / 4, 256, 0, stream>>>(outputs, W, p1, pE, flag, scores);
  scan_kernel<<<1, 256, 0, stream>>>(scores, (float*)d_out);
}

// Round 9
// 831.295 us; speedup vs baseline: 1.3204x; 1.3204x over previous
//
#include <hip/hip_runtime.h>
#include <stdint.h>
#include <math.h>

// Problem dims (fixed by reference setup_inputs)
#define NN 8
#define TT 256
#define BB 4
#define DD 512
#define VV 32000
#define MM (NN*TT*BB)          // 8192 rows

// MFMA GEMM tiling
#define TM 128
#define TN 128
#define VT 5                   // n-tiles swept per block
#define GX (VV/(TN*VT))        // 50
#define CHUNKS3 32             // 3-pass kernel: K=16 per chunk (2048 halves)
#define CHUNKS1 16             // 1-pass kernel: K=32 per chunk (4096 halves)

#define RCAP 2048              // max rescored rows (expect ~350)
#define MARGIN 3.0e5f          // scaled-units confidence margin (~15 sigma)

typedef _Float16 half8  __attribute__((ext_vector_type(8)));
typedef float    f32x4  __attribute__((ext_vector_type(4)));
typedef float    f32x16 __attribute__((ext_vector_type(16)));
typedef unsigned long long u64;

#define MFMA32(a,b,c) __builtin_amdgcn_mfma_f32_32x32x16_f16((a),(b),(c),0,0,0)
#define MFMA16(a,b,c) __builtin_amdgcn_mfma_f32_16x16x32_f16((a),(b),(c),0,0,0)

// ---- workspace layout ----
#define OFF_P1     0ull              // 64KB u64[8192]
#define OFF_P2     65536ull          // 64KB
#define OFF_PE     131072ull         // 64KB
#define OFF_FLAG   196608ull         // 32KB int[8192]
#define OFF_LIST   229376ull         // 8KB  int[2048]
#define OFF_CNT    237568ull         // 4KB pad
#define OFF_SCORES 241664ull         // 32KB
#define OFF_AH     294912ull
#define AH_SZ      8388608ull        // 8192*512*2 B
#define OFF_AL     (OFF_AH + AH_SZ)
#define OFF_WH     (OFF_AL + AH_SZ)
#define WH_SZ      32768000ull       // 32000*512*2 B
#define OFF_WL     (OFF_WH + WH_SZ)
#define OFF_CAH    (OFF_WL + WH_SZ)
#define CA_SZ      2097152ull        // 2048*512*2 B
#define OFF_CAL    (OFF_CAH + CA_SZ)
#define WS_NEED2   (OFF_CAL + CA_SZ)     // ~86.8 MB : full fast path
#define WS_NEED1   (OFF_WL + WH_SZ)      // ~82.6 MB : 3-pass-everywhere path

// ---------- helpers ----------

__device__ __forceinline__ uint32_t fkey(float v){
  uint32_t b = __float_as_uint(v);
  return b ^ ((b & 0x80000000u) ? 0xFFFFFFFFu : 0x80000000u);
}
__device__ __forceinline__ float unfkey(uint32_t k){
  uint32_t b = (k & 0x80000000u) ? (k ^ 0x80000000u) : ~k;
  return __uint_as_float(b);
}

__device__ __forceinline__ uint32_t rotl32(uint32_t x, int r){
  return (x << r) | (x >> (32 - r));
}
__device__ __forceinline__ void threefry2x32(uint32_t k0, uint32_t k1,
                                             uint32_t& x0, uint32_t& x1){
  const uint32_t ks0 = k0, ks1 = k1, ks2 = k0 ^ k1 ^ 0x1BD11BDAu;
  x0 += ks0; x1 += ks1;
  x0 += x1; x1 = rotl32(x1,13); x1 ^= x0;
  x0 += x1; x1 = rotl32(x1,15); x1 ^= x0;
  x0 += x1; x1 = rotl32(x1,26); x1 ^= x0;
  x0 += x1; x1 = rotl32(x1, 6); x1 ^= x0;
  x0 += ks1; x1 += ks2 + 1u;
  x0 += x1; x1 = rotl32(x1,17); x1 ^= x0;
  x0 += x1; x1 = rotl32(x1,29); x1 ^= x0;
  x0 += x1; x1 = rotl32(x1,16); x1 ^= x0;
  x0 += x1; x1 = rotl32(x1,24); x1 ^= x0;
  x0 += ks2; x1 += ks0 + 2u;
  x0 += x1; x1 = rotl32(x1,13); x1 ^= x0;
  x0 += x1; x1 = rotl32(x1,15); x1 ^= x0;
  x0 += x1; x1 = rotl32(x1,26); x1 ^= x0;
  x0 += x1; x1 = rotl32(x1, 6); x1 ^= x0;
  x0 += ks0; x1 += ks1 + 3u;
  x0 += x1; x1 = rotl32(x1,17); x1 ^= x0;
  x0 += x1; x1 = rotl32(x1,29); x1 ^= x0;
  x0 += x1; x1 = rotl32(x1,16); x1 ^= x0;
  x0 += x1; x1 = rotl32(x1,24); x1 ^= x0;
  x0 += ks1; x1 += ks2 + 4u;
  x0 += x1; x1 = rotl32(x1,13); x1 ^= x0;
  x0 += x1; x1 = rotl32(x1,15); x1 ^= x0;
  x0 += x1; x1 = rotl32(x1,26); x1 ^= x0;
  x0 += x1; x1 = rotl32(x1, 6); x1 ^= x0;
  x0 += ks2; x1 += ks0 + 5u;
}

__device__ __forceinline__ float uniform_from_bits(uint32_t bits){
  return __uint_as_float((bits >> 9) | 0x3f800000u) - 1.0f;
}

// async 16B global -> LDS (global addr per-lane, LDS dest wave-uniform + lane*16)
__device__ __forceinline__ void gload16(const _Float16* g, _Float16* l){
  __builtin_amdgcn_global_load_lds(
      (const __attribute__((address_space(1))) uint32_t*)g,
      (__attribute__((address_space(3))) uint32_t*)l, 16, 0, 0);
}

// ---------- kernel: init all header accumulators ----------
__global__ void init_kernel(u64* p1, u64* p2, u64* pE, int* flag, unsigned int* cnt){
  int i = blockIdx.x * blockDim.x + threadIdx.x;
  if (i < MM){ p1[i] = 0ULL; p2[i] = 0ULL; pE[i] = 0ULL; flag[i] = 0; }
  if (i == 0) *cnt = 0u;
}

// ---------- conversion: fp32 [rows,512] -> split-f16 planes, tile layout ------
// hi = f16(x*scale), lo = f16(x*scale - hi) [natural residual].
// Plane chunk c = rt*8192 + kc*128 + rin (kc=k/8 in 0..63), 8 halves each.
__global__ __launch_bounds__(256)
void convert_kernel(const float* __restrict__ src,
                    _Float16* __restrict__ hi, _Float16* __restrict__ lo,
                    float scale){
  const int k0 = blockIdx.x & 15;       // 32-k slab
  const int rt = blockIdx.x >> 4;
  __shared__ _Float16 hbuf[4096], lbuf[4096];
  const int t = threadIdx.x;
  #pragma unroll
  for (int i = 0; i < 4; ++i){
    const int f = i * 256 + t;
    const int rin = f >> 3, c4 = f & 7;
    const float4 v4 = *(const float4*)&src[(size_t)(rt*128+rin)*DD + k0*32 + c4*4];
    const int base = (c4 >> 1) * 1024 + rin * 8 + (c4 & 1) * 4;
    float vv[4] = {v4.x, v4.y, v4.z, v4.w};
    #pragma unroll
    for (int j = 0; j < 4; ++j){
      const float s = vv[j] * scale;
      const _Float16 hh = (_Float16)s;
      hbuf[base + j] = hh;
      lbuf[base + j] = (_Float16)(s - (float)hh);
    }
  }
  __syncthreads();
  const size_t ob = ((size_t)rt * 8192 + (size_t)k0 * 512) * 8;
  #pragma unroll
  for (int i = 0; i < 2; ++i){
    const int cl = i * 256 + t;
    *(half8*)&hi[ob + (size_t)cl * 8] = *(const half8*)&hbuf[cl * 8];
    *(half8*)&lo[ob + (size_t)cl * 8] = *(const half8*)&lbuf[cl * 8];
  }
}

// ---------- kernel A: 1-pass hi*hi MFMA GEMM + top-2 tracking epilogue --------
// K=32 chunks, double-buffered; 34KB LDS -> 4 blocks/CU at (256,4).
// Epilogue: vt==0 seeds lmax1/lmax2 via pairwise top-2 butterfly; vt>0 uses
// threshold-filtered LDS atomics (broadcast read of lmax2, rare atomics).
__global__ __launch_bounds__(256, 4)
void gemm1_kernel(const _Float16* __restrict__ Ahp, const _Float16* __restrict__ Whp,
                  u64* __restrict__ p1, u64* __restrict__ p2){
  __shared__ __align__(16) _Float16 sAh[2][4096], sBh[2][4096];
  __shared__ u64 lmax1[TM], lmax2[TM];

  const int tid = threadIdx.x, wid = tid >> 6, lane = tid & 63;
  const int l31 = lane & 31, lhi = lane >> 5;
  const int wave_m = (wid & 1) * 64, wave_n = (wid >> 1) * 64;
  const int by = blockIdx.x;            // row-tile (fastest -> same-XCD A reuse)
  const int bx = blockIdx.y;            // W-group

  if (tid < TM){ lmax1[tid] = 0ULL; lmax2[tid] = 0ULL; }

  // staging: wid0/1 -> sAh halves, wid2/3 -> sBh halves
  const int half_off = (wid & 1) * 2048;

  for (int vt = 0; vt < VT; ++vt){
    const int nt = bx * VT + vt;

    f32x16 acc[2][2];
    #pragma unroll
    for (int i = 0; i < 2; ++i)
      #pragma unroll
      for (int j = 0; j < 2; ++j) acc[i][j] = (f32x16)0.0f;

    const _Float16* gplane = (wid < 2) ? Ahp + (size_t)by * 65536
                                       : Whp + (size_t)nt * 65536;
    _Float16* stg0 = ((wid < 2) ? sAh[0] : sBh[0]) + half_off;
    _Float16* stg1 = ((wid < 2) ? sAh[1] : sBh[1]) + half_off;

    { // stage chunk 0
      const _Float16* g = gplane + half_off + lane * 8;
      #pragma unroll
      for (int j = 0; j < 4; ++j) gload16(g + j * 512, stg0 + j * 512);
    }

    for (int kk = 0; kk < CHUNKS1; ++kk){
      __syncthreads();                  // buf[kk&1] ready
      if (kk < CHUNKS1 - 1){
        const _Float16* g = gplane + (size_t)(kk + 1) * 4096 + half_off + lane * 8;
        _Float16* s = (kk & 1) ? stg0 : stg1;
        #pragma unroll
        for (int j = 0; j < 4; ++j) gload16(g + j * 512, s + j * 512);
      }
      const int cb = kk & 1;

      // chunk layout [kc 4][row 128][8]; MFMA ks: kc = ks*2 + lhi
      half8 fah[2][2], fbh[2][2];
      #pragma unroll
      for (int ks = 0; ks < 2; ++ks){
        const int kcb = (ks * 2 + lhi) * 128;
        #pragma unroll
        for (int t = 0; t < 2; ++t){
          fah[ks][t] = *(const half8*)&sAh[cb][(kcb + wave_m + t * 32 + l31) * 8];
          fbh[ks][t] = *(const half8*)&sBh[cb][(kcb + wave_n + t * 32 + l31) * 8];
        }
      }
      #pragma unroll
      for (int ks = 0; ks < 2; ++ks)
        #pragma unroll
        for (int ti = 0; ti < 2; ++ti)
          #pragma unroll
          for (int tj = 0; tj < 2; ++tj)
            acc[ti][tj] = MFMA32(fah[ks][ti], fbh[ks][tj], acc[ti][tj]);
    }

    // top-2 epilogue. C/D: col=lane&31, row=(v&3)+8*(v>>2)+4*lhi.
    const int ncol0 = nt * TN + wave_n;
    if (vt == 0){
      #pragma unroll
      for (int ti = 0; ti < 2; ++ti){
        #pragma unroll
        for (int v = 0; v < 16; ++v){
          const int mloc = wave_m + ti * 32 + (v & 3) + 8 * (v >> 2) + 4 * lhi;
          u64 ca = ((u64)fkey(acc[ti][0][v]) << 32) | (u64)(~(uint32_t)(ncol0 + l31));
          u64 cb2 = ((u64)fkey(acc[ti][1][v]) << 32) | (u64)(~(uint32_t)(ncol0 + 32 + l31));
          u64 q1 = ca > cb2 ? ca : cb2;
          u64 q2 = ca > cb2 ? cb2 : ca;
          #pragma unroll
          for (int m = 16; m > 0; m >>= 1){   // pairwise top-2 over 32-lane group
            u64 o1 = __shfl_xor(q1, m, 64);
            u64 o2 = __shfl_xor(q2, m, 64);
            if (o1 > q1){ q2 = (q1 > o2) ? q1 : o2; q1 = o1; }
            else        { q2 = (q2 > o1) ? q2 : o1; }
          }
          if (l31 == 0){
            u64 old = atomicMax(&lmax1[mloc], q1);
            u64 loser = old < q1 ? old : q1;
            atomicMax(&lmax2[mloc], loser);
            atomicMax(&lmax2[mloc], q2);
          }
        }
      }
    } else {
      // filtered atomics: only candidates beating the row's running 2nd max
      #pragma unroll
      for (int ti = 0; ti < 2; ++ti){
        #pragma unroll
        for (int v = 0; v < 16; ++v){
          const int mloc = wave_m + ti * 32 + (v & 3) + 8 * (v >> 2) + 4 * lhi;
          const uint32_t ka = fkey(acc[ti][0][v]);
          const uint32_t kb = fkey(acc[ti][1][v]);
          const uint32_t thr = (uint32_t)(lmax2[mloc] >> 32);   // broadcast read
          if (ka > thr){
            const u64 pk = ((u64)ka << 32) | (u64)(~(uint32_t)(ncol0 + l31));
            const u64 old = atomicMax(&lmax1[mloc], pk);
            const u64 lo = old < pk ? old : pk;
            atomicMax(&lmax2[mloc], lo);
          }
          if (kb > thr){
            const u64 pk = ((u64)kb << 32) | (u64)(~(uint32_t)(ncol0 + 32 + l31));
            const u64 old = atomicMax(&lmax1[mloc], pk);
            const u64 lo = old < pk ? old : pk;
            atomicMax(&lmax2[mloc], lo);
          }
        }
      }
    }
  }

  __syncthreads();
  if (tid < TM){
    const int g = by * TM + tid;
    u64 l1 = lmax1[tid], l2 = lmax2[tid];
    u64 old = atomicMax(&p1[g], l1);
    u64 loser = old < l1 ? old : l1;
    atomicMax(&p2[g], loser);
    atomicMax(&p2[g], l2);
  }
}

// ---------- kernel: resolve confident vs borderline rows ----------
__global__ void resolve_kernel(const u64* __restrict__ p1, const u64* __restrict__ p2,
                               int* __restrict__ flag, int* __restrict__ list,
                               unsigned int* __restrict__ cnt){
  const int r = blockIdx.x * blockDim.x + threadIdx.x;
  if (r >= MM) return;
  const float f1 = unfkey((uint32_t)(p1[r] >> 32));
  const float f2 = unfkey((uint32_t)(p2[r] >> 32));
  if (f1 - f2 <= MARGIN){
    const unsigned int idx = atomicAdd(cnt, 1u);
    if (idx < RCAP){ list[idx] = r; flag[r] = 1; }
  }
}

// ---------- kernel: compact borderline rows' planes into CA tiles ----------
__global__ void compact_kernel(const _Float16* __restrict__ Ahp,
                               const _Float16* __restrict__ Alp,
                               _Float16* __restrict__ CAh, _Float16* __restrict__ CAl,
                               const int* __restrict__ list,
                               const unsigned int* __restrict__ cnt){
  const int cid = blockIdx.x * 256 + threadIdx.x;   // 0..131071 (2048 rows x 64 chunks)
  const int i = cid >> 6, kc = cid & 63;
  const unsigned int c = *cnt;
  const unsigned int lim = ((c < RCAP ? c : RCAP) + 127u) & ~127u;
  if ((unsigned int)i >= lim) return;
  const int g = ((unsigned int)i < c) ? list[i] : list[0];
  const size_t src = ((size_t)(g >> 7) * 8192 + (size_t)kc * 128 + (g & 127)) * 8;
  const size_t dst = ((size_t)(i >> 7) * 8192 + (size_t)kc * 128 + (i & 127)) * 8;
  *(half8*)&CAh[dst] = *(const half8*)&Ahp[src];
  *(half8*)&CAl[dst] = *(const half8*)&Alp[src];
}

// ---------- kernel B: 3-pass split-f16 GEMM + argmax (full or gathered) -------
// acc = ah*bh + ah*bl + al*bh (single accumulator; round-7-verified).
__global__ __launch_bounds__(256, 4)
void gemm3_kernel(const _Float16* __restrict__ Ahp, const _Float16* __restrict__ Alp,
                  const _Float16* __restrict__ Whp, const _Float16* __restrict__ Wlp,
                  u64* __restrict__ out,
                  const int* __restrict__ rowlist,
                  const unsigned int* __restrict__ cntp){
  if (cntp && (unsigned int)(blockIdx.x * TM) >= *cntp) return;

  __shared__ __align__(16) _Float16 sAh[2][2048], sAl[2][2048], sBh[2][2048], sBl[2][2048];
  __shared__ u64 lmax[TM];

  const int tid = threadIdx.x, wid = tid >> 6, lane = tid & 63;
  const int l31 = lane & 31, lhi = lane >> 5;
  const int wave_m = (wid & 1) * 64, wave_n = (wid >> 1) * 64;
  const int by = blockIdx.x;
  const int bx = blockIdx.y;

  if (tid < TM) lmax[tid] = 0ULL;

  _Float16* stg0 = (wid == 0) ? sAh[0] : (wid == 1) ? sAl[0] : (wid == 2) ? sBh[0] : sBl[0];
  _Float16* stg1 = (wid == 0) ? sAh[1] : (wid == 1) ? sAl[1] : (wid == 2) ? sBh[1] : sBl[1];

  for (int vt = 0; vt < VT; ++vt){
    const int nt = bx * VT + vt;

    f32x16 acc[2][2];
    #pragma unroll
    for (int i = 0; i < 2; ++i)
      #pragma unroll
      for (int j = 0; j < 2; ++j) acc[i][j] = (f32x16)0.0f;

    const _Float16* gbase =
        (wid == 0) ? Ahp + (size_t)by * 65536 : (wid == 1) ? Alp + (size_t)by * 65536
      : (wid == 2) ? Whp + (size_t)nt * 65536 :              Wlp + (size_t)nt * 65536;

    {
      const _Float16* g = gbase + lane * 8;
      #pragma unroll
      for (int j = 0; j < 4; ++j) gload16(g + j * 512, stg0 + j * 512);
    }

    for (int kk = 0; kk < CHUNKS3; ++kk){
      __syncthreads();
      if (kk < CHUNKS3 - 1){
        const _Float16* g = gbase + (size_t)(kk + 1) * 2048 + lane * 8;
        _Float16* s = (kk & 1) ? stg0 : stg1;
        #pragma unroll
        for (int j = 0; j < 4; ++j) gload16(g + j * 512, s + j * 512);
      }
      const int cb = kk & 1;

      half8 fah[2], fal[2], fbh[2], fbl[2];
      #pragma unroll
      for (int t = 0; t < 2; ++t){
        const int ra = lhi * 128 + wave_m + t * 32 + l31;
        const int rb = lhi * 128 + wave_n + t * 32 + l31;
        fah[t] = *(const half8*)&sAh[cb][ra * 8];
        fal[t] = *(const half8*)&sAl[cb][ra * 8];
        fbh[t] = *(const half8*)&sBh[cb][rb * 8];
        fbl[t] = *(const half8*)&sBl[cb][rb * 8];
      }
      #pragma unroll
      for (int ti = 0; ti < 2; ++ti)
        #pragma unroll
        for (int tj = 0; tj < 2; ++tj){
          acc[ti][tj] = MFMA32(fah[ti], fbh[tj], acc[ti][tj]);
          acc[ti][tj] = MFMA32(fah[ti], fbl[tj], acc[ti][tj]);
          acc[ti][tj] = MFMA32(fal[ti], fbh[tj], acc[ti][tj]);
        }
    }

    const int ncol0 = nt * TN + wave_n;
    #pragma unroll
    for (int ti = 0; ti < 2; ++ti){
      #pragma unroll
      for (int v = 0; v < 16; ++v){
        const int mloc = wave_m + ti * 32 + (v & 3) + 8 * (v >> 2) + 4 * lhi;
        u64 best = 0ULL;
        #pragma unroll
        for (int tj = 0; tj < 2; ++tj){
          const int col = ncol0 + tj * 32 + l31;
          const u64 p = ((u64)fkey(acc[ti][tj][v]) << 32) | (u64)(~(uint32_t)col);
          if (p > best) best = p;
        }
        #pragma unroll
        for (int m = 16; m > 0; m >>= 1){
          const u64 o = __shfl_xor(best, m, 64);
          if (o > best) best = o;
        }
        if (l31 == 0) atomicMax(&lmax[mloc], best);
      }
    }
  }

  __syncthreads();
  if (tid < TM){
    int g;
    if (rowlist){
      const int i = by * TM + tid;
      const unsigned int c = *cntp;
      g = ((unsigned int)i < c) ? rowlist[i] : rowlist[0];
    } else {
      g = by * TM + tid;
    }
    atomicMax(&out[g], lmax[tid]);
  }
}

// ---------- fallback (round-3 verified): in-loop-convert GEMM ----------
__device__ __forceinline__ void cvt8(const float4& p, const float4& q, float scale,
                                     half8& h, half8& l){
  float v[8] = {p.x,p.y,p.z,p.w,q.x,q.y,q.z,q.w};
  #pragma unroll
  for (int j = 0; j < 8; ++j){
    const float s = v[j] * scale;
    const _Float16 hh = (_Float16)s;
    h[j] = hh;
    l[j] = (_Float16)((s - (float)hh) * 4096.0f);
  }
}

#define FBK 32
__global__ __launch_bounds__(256, 2)
void gemm_fallback_kernel(const float* __restrict__ A,
                          const float* __restrict__ W,
                          u64* __restrict__ packed){
  __shared__ __align__(16) _Float16 Ah[TM][40];
  __shared__ __align__(16) _Float16 Al[TM][40];
  __shared__ __align__(16) _Float16 Bh[TN][40];
  __shared__ __align__(16) _Float16 Bl[TN][40];
  __shared__ u64 lmax[TM];

  const int tid   = threadIdx.x;
  const int mtile = blockIdx.y * TM;
  const int wid    = tid >> 6;
  const int lane   = tid & 63;
  const int lm     = lane & 15;
  const int lk     = lane >> 4;
  const int wave_m = (wid & 1) * 64;
  const int wave_n = (wid >> 1) * 64;
  const int srow = tid >> 2;
  const int skc  = (tid & 3) * 8;

  if (tid < TM) lmax[tid] = 0ULL;

  for (int vt = 0; vt < VT; ++vt){
    const int ntile = (blockIdx.x * VT + vt) * TN;
    f32x4 acc1[4][4], acc2[4][4];
    #pragma unroll
    for (int i = 0; i < 4; ++i)
      #pragma unroll
      for (int j = 0; j < 4; ++j){ acc1[i][j] = (f32x4)0.0f; acc2[i][j] = (f32x4)0.0f; }

    for (int k0 = 0; k0 < DD; k0 += FBK){
      const float* pa0 = &A[(size_t)(mtile + srow     ) * DD + k0 + skc];
      const float* pa1 = &A[(size_t)(mtile + srow + 64) * DD + k0 + skc];
      const float* pb0 = &W[(size_t)(ntile + srow     ) * DD + k0 + skc];
      const float* pb1 = &W[(size_t)(ntile + srow + 64) * DD + k0 + skc];
      const float4 a00 = *(const float4*)(pa0), a01 = *(const float4*)(pa0 + 4);
      const float4 a10 = *(const float4*)(pa1), a11 = *(const float4*)(pa1 + 4);
      const float4 b00 = *(const float4*)(pb0), b01 = *(const float4*)(pb0 + 4);
      const float4 b10 = *(const float4*)(pb1), b11 = *(const float4*)(pb1 + 4);

      __syncthreads();
      half8 h, l;
      cvt8(a00, a01, 4096.0f,  h, l);
      *(half8*)&Ah[srow     ][skc] = h; *(half8*)&Al[srow     ][skc] = l;
      cvt8(a10, a11, 4096.0f,  h, l);
      *(half8*)&Ah[srow + 64][skc] = h; *(half8*)&Al[srow + 64][skc] = l;
      cvt8(b00, b01, 16384.0f, h, l);
      *(half8*)&Bh[srow     ][skc] = h; *(half8*)&Bl[srow     ][skc] = l;
      cvt8(b10, b11, 16384.0f, h, l);
      *(half8*)&Bh[srow + 64][skc] = h; *(half8*)&Bl[srow + 64][skc] = l;
      __syncthreads();

      half8 ah[4], al[4], bh[4], bl[4];
      #pragma unroll
      for (int ti = 0; ti < 4; ++ti){
        const int r = wave_m + ti * 16 + lm;
        ah[ti] = *(const half8*)&Ah[r][lk * 8];
        al[ti] = *(const half8*)&Al[r][lk * 8];
      }
      #pragma unroll
      for (int tj = 0; tj < 4; ++tj){
        const int r = wave_n + tj * 16 + lm;
        bh[tj] = *(const half8*)&Bh[r][lk * 8];
        bl[tj] = *(const half8*)&Bl[r][lk * 8];
      }
      #pragma unroll
      for (int ti = 0; ti < 4; ++ti)
        #pragma unroll
        for (int tj = 0; tj < 4; ++tj){
          acc1[ti][tj] = MFMA16(ah[ti], bh[tj], acc1[ti][tj]);
          acc2[ti][tj] = MFMA16(ah[ti], bl[tj], acc2[ti][tj]);
          acc2[ti][tj] = MFMA16(al[ti], bh[tj], acc2[ti][tj]);
        }
    }

    #pragma unroll
    for (int ti = 0; ti < 4; ++ti){
      #pragma unroll
      for (int v = 0; v < 4; ++v){
        const int mloc = wave_m + ti * 16 + lk * 4 + v;
        u64 best = 0ULL;
        #pragma unroll
        for (int tj = 0; tj < 4; ++tj){
          const int col = ntile + wave_n + tj * 16 + lm;
          const float lg = acc1[ti][tj][v] + acc2[ti][tj][v] * (1.0f/4096.0f);
          const u64 p = ((u64)fkey(lg) << 32) | (u64)(~(uint32_t)col);
          if (p > best) best = p;
        }
        atomicMax(&lmax[mloc], best);
      }
    }
  }

  __syncthreads();
  if (tid < TM) atomicMax(&packed[mtile + tid], lmax[tid]);
}

// ---------- kernel: scores[r] = sqrt(D) * dot(outputs[n,t,:], W[argmax_r]) ----
__global__ __launch_bounds__(256)
void score_kernel(const float* __restrict__ outputs,
                  const float* __restrict__ W,
                  const u64* __restrict__ p1, const u64* __restrict__ pE,
                  const int* __restrict__ flag,
                  float* __restrict__ scores){
  const int wave = threadIdx.x >> 6;
  const int lane = threadIdx.x & 63;
  const int r = blockIdx.x * 4 + wave;
  const u64 pk = flag[r] ? pE[r] : p1[r];
  const uint32_t idx = ~(uint32_t)pk;
  const int n = r >> 10;
  const int t = (r >> 2) & (TT - 1);
  const float* ov = outputs + ((size_t)(n * TT + t) << 9);
  const float* wv = W + (size_t)idx * DD;
  float s = 0.0f;
  #pragma unroll
  for (int j = 0; j < 8; ++j){
    const int d = lane + j * 64;
    s = fmaf(ov[d], wv[d], s);
  }
  #pragma unroll
  for (int off = 32; off > 0; off >>= 1) s += __shfl_down(s, off);
  if (lane == 0) scores[r] = s * 22.62741699796952f;  // float32(sqrt(512))
}

// ---------- kernel: sequential accept/reject scan + mask scatter ----------
__global__ __launch_bounds__(256)
void scan_kernel(const float* __restrict__ scores, float* __restrict__ mask_out){
  __shared__ float sc[MM];
  __shared__ float uu[TT * NN];

  const int tid = threadIdx.x;

  for (int i = tid; i < MM; i += 256){
    mask_out[i] = 0.0f;
    sc[i] = scores[i];
  }

  // Partitionable threefry (JAX >= 0.4.36): key' = tf2x32((0,42),(0,t));
  // element n: (o0,o1) = tf2x32(key',(0,n)); bits = o0^o1.
  {
    const int t = tid;
    uint32_t k0 = 0u, k1 = (uint32_t)t;
    threefry2x32(0u, 42u, k0, k1);
    #pragma unroll
    for (int n = 0; n < NN; ++n){
      uint32_t x0 = 0u, x1 = (uint32_t)n;
      threefry2x32(k0, k1, x0, x1);
      uu[t * NN + n] = uniform_from_bits(x0 ^ x1);
    }
  }
  __syncthreads();

  if (tid < NN){
    const int n = tid;
    int x = 0, y = 0;
    for (int t = 0; t < TT; ++t){
      const int idx0 = x * BB + y;
      mask_out[n * (TT * BB) + idx0] = 1.0f;
      const float scx0 = sc[n * (TT * BB) + idx0];
      const float scx1 = sc[n * (TT * BB) + t * BB];
      const float prob = 1.0f / (1.0f + expf(-((scx0 - scx1) / 10.0f)));
      int accept = (uu[t * NN + n] < prob) ? 1 : 0;
      if (y + accept >= BB) accept = 0;
      y = (y + accept) * accept;
      x = x * accept + (t + 1) * (1 - accept);
    }
  }
}

// ---------- launcher ----------
extern "C" void kernel_launch(void* const* d_in, const int* in_sizes, int n_in,
                              void* d_out, int out_size, void* d_ws, size_t ws_size,
                              hipStream_t stream){
  const float* outputs       = (const float*)d_in[0];   // [8,256,512]
  const float* block_outputs = (const float*)d_in[1];   // [8,256,4,512]
  const float* W             = (const float*)d_in[2];   // [32000,512]

  u64* p1   = (u64*)((char*)d_ws + OFF_P1);
  u64* p2   = (u64*)((char*)d_ws + OFF_P2);
  u64* pE   = (u64*)((char*)d_ws + OFF_PE);
  int* flag = (int*)((char*)d_ws + OFF_FLAG);
  int* list = (int*)((char*)d_ws + OFF_LIST);
  unsigned int* cnt = (unsigned int*)((char*)d_ws + OFF_CNT);
  float* scores = (float*)((char*)d_ws + OFF_SCORES);

  init_kernel<<<MM / 256, 256, 0, stream>>>(p1, p2, pE, flag, cnt);

  if (ws_size >= WS_NEED2){
    _Float16* Ahp = (_Float16*)((char*)d_ws + OFF_AH);
    _Float16* Alp = (_Float16*)((char*)d_ws + OFF_AL);
    _Float16* Whp = (_Float16*)((char*)d_ws + OFF_WH);
    _Float16* Wlp = (_Float16*)((char*)d_ws + OFF_WL);
    _Float16* CAh = (_Float16*)((char*)d_ws + OFF_CAH);
    _Float16* CAl = (_Float16*)((char*)d_ws + OFF_CAL);
    convert_kernel<<<(MM / 128) * 16, 256, 0, stream>>>(block_outputs, Ahp, Alp, 4096.0f);
    convert_kernel<<<(VV / 128) * 16, 256, 0, stream>>>(W, Whp, Wlp, 16384.0f);
    // pass 1: hi*hi approximate logits + top-2 per row
    gemm1_kernel<<<dim3(MM / TM, GX), 256, 0, stream>>>(Ahp, Whp, p1, p2);
    // flag rows whose top-2 gap is within the error margin
    resolve_kernel<<<MM / 256, 256, 0, stream>>>(p1, p2, flag, list, cnt);
    // gather borderline rows, exact 3-pass rescore of those rows only
    compact_kernel<<<(RCAP * 64) / 256, 256, 0, stream>>>(Ahp, Alp, CAh, CAl, list, cnt);
    gemm3_kernel<<<dim3(RCAP / TM, GX), 256, 0, stream>>>(CAh, CAl, Whp, Wlp, pE, list, cnt);
  } else if (ws_size >= WS_NEED1){
    _Float16* Ahp = (_Float16*)((char*)d_ws + OFF_AH);
    _Float16* Alp = (_Float16*)((char*)d_ws + OFF_AL);
    _Float16* Whp = (_Float16*)((char*)d_ws + OFF_WH);
    _Float16* Wlp = (_Float16*)((char*)d_ws + OFF_WL);
    convert_kernel<<<(MM / 128) * 16, 256, 0, stream>>>(block_outputs, Ahp, Alp, 4096.0f);
    convert_kernel<<<(VV / 128) * 16, 256, 0, stream>>>(W, Whp, Wlp, 16384.0f);
    gemm3_kernel<<<dim3(MM / TM, GX), 256, 0, stream>>>(Ahp, Alp, Whp, Wlp, p1,
                                                        nullptr, nullptr);
  } else {
    gemm_fallback_kernel<<<dim3(GX, MM / TM), 256, 0, stream>>>(block_outputs, W, p1);
  }

  score_kernel<<<MM / 4, 256, 0, stream>>>(outputs, W, p1, pE, flag, scores);
  scan_kernel<<<1, 256, 0, stream>>>(scores, (float*)d_out);
}